// Round 1
// baseline (1103.990 us; speedup 1.0000x reference)
//
#include <hip/hip_runtime.h>
#include <math.h>

#define Bc  32
#define Cc  512
#define HWc 784
#define Mc  200
#define Kc  5
#define NCc 50
#define PT  16
#define MT  32
#define CK  4
#define NMTILES 7   // ceil(200/32)
#define NPTILES 49  // 784/16

// ---------------- K1: background log-likelihood ----------------
// bg[b][k][hw] = log(0.3 * sum_c x[b,c,hw]*cl_norm[k,c] + 1e-10)
__global__ __launch_bounds__(256) void k_bg(const float* __restrict__ x,
                                            const float* __restrict__ clut,
                                            float* __restrict__ bg) {
    __shared__ float cl[Kc][Cc];
    __shared__ float csum[Kc];
    const int t = threadIdx.x;
    for (int i = t; i < Kc * Cc; i += 256) {
        float v = clut[i];
        cl[i >> 9][i & 511] = fminf(fmaxf(v, 0.0f), 1.0f);
    }
    __syncthreads();
    if (t < Kc) {
        float s = 0.0f;
        for (int c = 0; c < Cc; ++c) s += cl[t][c];
        csum[t] = fmaxf(s, 1e-12f);
    }
    __syncthreads();
    for (int i = t; i < Kc * Cc; i += 256) {
        cl[i >> 9][i & 511] = cl[i >> 9][i & 511] / csum[i >> 9];
    }
    __syncthreads();

    const int b  = blockIdx.x;
    const int hw = blockIdx.y * 256 + t;
    if (hw < HWc) {
        float acc[Kc] = {0.f, 0.f, 0.f, 0.f, 0.f};
        const float* xb = x + (size_t)b * Cc * HWc + hw;
        for (int c = 0; c < Cc; ++c) {
            float xv = xb[(size_t)c * HWc];
#pragma unroll
            for (int k = 0; k < Kc; ++k) acc[k] = fmaf(xv, cl[k][c], acc[k]);
        }
#pragma unroll
        for (int k = 0; k < Kc; ++k)
            bg[((size_t)b * Kc + k) * HWc + hw] = logf(acc[k] * 0.3f + 1e-10f);
    }
}

// ---------------- K2: foreground log-likelihood (the big one) ----------------
// fg[m][b][hw] = log(0.7 * (sum_c x[b,c,hw]*clamp(mm[m,c,hw])) / max(S[m,hw],1e-12) + 1e-10)
// Block: MT=32 m x PT=16 pix x all 32 b.  Thread: 8b x 8m x 1pix.
__global__ __launch_bounds__(256, 4) void k_fg(const float* __restrict__ x,
                                               const float* __restrict__ mm,
                                               float* __restrict__ fg) {
    // raw staging (global layout, pix-contiguous), rows padded 16->20 floats
    __shared__ float rawX[CK][Bc][20];
    __shared__ float rawM[CK][MT][20];
    // transposed (b/m contiguous), rows padded 32->36 floats
    __shared__ float xT[CK][PT][36];
    __shared__ float mT[CK][PT][36];

    const int t    = threadIdx.x;
    const int pixl = t & 3;
    const int mg   = (t >> 2) & 3;
    const int bgp  = (t >> 4) & 3;
    const int pixh = t >> 6;
    const int pix  = pixl + 4 * pixh;       // 0..15
    const int mtile = blockIdx.x % NMTILES;
    const int ptile = blockIdx.x / NMTILES;
    const int pix0 = ptile * PT;
    const int m0   = mtile * MT;
    const int b0   = bgp * 8;
    const int mf0  = mg * 8;

    float acc[8][8];
#pragma unroll
    for (int i = 0; i < 8; ++i)
#pragma unroll
        for (int j = 0; j < 8; ++j) acc[i][j] = 0.0f;
    float sacc[8] = {0.f, 0.f, 0.f, 0.f, 0.f, 0.f, 0.f, 0.f};

    for (int cc = 0; cc < Cc; cc += CK) {
        __syncthreads();
        // ---- phase A: global -> LDS raw (coalesced float4 along pix) ----
#pragma unroll
        for (int r = 0; r < 2; ++r) {
            const int j   = t + 256 * r;          // 0..511
            const int q   = j & 3;                // pix quad
            const int cx  = (j >> 2) & 3;         // c within chunk
            const int row = j >> 4;               // 0..31 (b for x, mrel for mm)
            const float4 xv4 = *(const float4*)(x + ((size_t)row * Cc + cc + cx) * HWc + pix0 + 4 * q);
            *(float4*)&rawX[cx][row][4 * q] = xv4;

            const int m = m0 + row;
            float4 mv4;
            if (m < Mc) {
                mv4 = *(const float4*)(mm + ((size_t)m * Cc + cc + cx) * HWc + pix0 + 4 * q);
                mv4.x = fminf(fmaxf(mv4.x, 0.0f), 1.0f);
                mv4.y = fminf(fmaxf(mv4.y, 0.0f), 1.0f);
                mv4.z = fminf(fmaxf(mv4.z, 0.0f), 1.0f);
                mv4.w = fminf(fmaxf(mv4.w, 0.0f), 1.0f);
            } else {
                mv4 = make_float4(0.f, 0.f, 0.f, 0.f);
            }
            *(float4*)&rawM[cx][row][4 * q] = mv4;
        }
        __syncthreads();
        // ---- phase B: LDS transpose (b-fastest lanes -> conflict-free b32 writes) ----
#pragma unroll
        for (int r = 0; r < 2; ++r) {
            const int j2 = t + 256 * r;           // 0..511
            const int r2 = j2 & 31;               // row (b / mrel), fastest across lanes
            const int c2 = (j2 >> 5) & 3;
            const int q2 = j2 >> 7;               // 0..3
            const float4 v = *(const float4*)&rawX[c2][r2][4 * q2];
            xT[c2][4 * q2 + 0][r2] = v.x;
            xT[c2][4 * q2 + 1][r2] = v.y;
            xT[c2][4 * q2 + 2][r2] = v.z;
            xT[c2][4 * q2 + 3][r2] = v.w;
            const float4 w = *(const float4*)&rawM[c2][r2][4 * q2];
            mT[c2][4 * q2 + 0][r2] = w.x;
            mT[c2][4 * q2 + 1][r2] = w.y;
            mT[c2][4 * q2 + 2][r2] = w.z;
            mT[c2][4 * q2 + 3][r2] = w.w;
        }
        __syncthreads();
        // ---- phase C: main compute, all-b128 fragment reads ----
#pragma unroll
        for (int c = 0; c < CK; ++c) {
            float xv[8], mv[8];
            *(float4*)&xv[0] = *(const float4*)&xT[c][pix][b0];
            *(float4*)&xv[4] = *(const float4*)&xT[c][pix][b0 + 4];
            *(float4*)&mv[0] = *(const float4*)&mT[c][pix][mf0];
            *(float4*)&mv[4] = *(const float4*)&mT[c][pix][mf0 + 4];
#pragma unroll
            for (int j = 0; j < 8; ++j) sacc[j] += mv[j];
#pragma unroll
            for (int i = 0; i < 8; ++i)
#pragma unroll
                for (int j = 0; j < 8; ++j)
                    acc[i][j] = fmaf(xv[i], mv[j], acc[i][j]);
        }
    }

    // ---- epilogue: normalize, log, store fg[m][b][hw] ----
    const int hw = pix0 + pix;
#pragma unroll
    for (int j = 0; j < 8; ++j) {
        const int m = m0 + mf0 + j;
        if (m < Mc) {
            const float scale = 0.7f / fmaxf(sacc[j], 1e-12f);
#pragma unroll
            for (int i = 0; i < 8; ++i) {
                fg[((size_t)m * Bc + b0 + i) * HWc + hw] = logf(acc[i][j] * scale + 1e-10f);
            }
        }
    }
}

// ---------------- K3: per (b,m): sum over pixels of max(fg,bg_k), then max over k ----------------
__global__ __launch_bounds__(128) void k_red(const float* __restrict__ fg,
                                             const float* __restrict__ bg,
                                             float* __restrict__ pm) {
    const int bm = blockIdx.x;      // b*200 + m
    const int b = bm / Mc;
    const int m = bm % Mc;
    const int t = threadIdx.x;
    const float* fgp = fg + ((size_t)m * Bc + b) * HWc;
    const float* bgb = bg + (size_t)b * Kc * HWc;
    float s[Kc] = {0.f, 0.f, 0.f, 0.f, 0.f};
    for (int hw = t; hw < HWc; hw += 128) {
        const float f = fgp[hw];
#pragma unroll
        for (int k = 0; k < Kc; ++k) s[k] += fmaxf(f, bgb[k * HWc + hw]);
    }
#pragma unroll
    for (int off = 32; off > 0; off >>= 1) {
#pragma unroll
        for (int k = 0; k < Kc; ++k) s[k] += __shfl_down(s[k], off, 64);
    }
    __shared__ float red[2][Kc];
    const int wv = t >> 6, ln = t & 63;
    if (ln == 0) {
#pragma unroll
        for (int k = 0; k < Kc; ++k) red[wv][k] = s[k];
    }
    __syncthreads();
    if (t == 0) {
        float best = -INFINITY;
#pragma unroll
        for (int k = 0; k < Kc; ++k) best = fmaxf(best, red[0][k] + red[1][k]);
        pm[bm] = best;
    }
}

// ---------------- K4: max over NM mixtures ----------------
__global__ void k_out(const float* __restrict__ pm, float* __restrict__ out) {
    const int i = blockIdx.x * 256 + threadIdx.x;   // b*50 + nc
    if (i < Bc * NCc) {
        const int b = i / NCc, nc = i % NCc;
        const float* p = pm + (size_t)b * Mc + nc * 4;
        out[i] = fmaxf(fmaxf(p[0], p[1]), fmaxf(p[2], p[3]));
    }
}

extern "C" void kernel_launch(void* const* d_in, const int* in_sizes, int n_in,
                              void* d_out, int out_size, void* d_ws, size_t ws_size,
                              hipStream_t stream) {
    const float* x    = (const float*)d_in[0];
    const float* mixm = (const float*)d_in[1];
    const float* clut = (const float*)d_in[2];
    float* out = (float*)d_out;

    float* bg = (float*)d_ws;                              // 32*5*784
    float* fg = bg + (size_t)Bc * Kc * HWc;                // 200*32*784
    float* pm = fg + (size_t)Mc * Bc * HWc;                // 32*200
    // total ws use: ~20.6 MB

    k_bg <<<dim3(32, 4), 256, 0, stream>>>(x, clut, bg);
    k_fg <<<dim3(NMTILES * NPTILES), 256, 0, stream>>>(x, mixm, fg);
    k_red<<<dim3(Bc * Mc), 128, 0, stream>>>(fg, bg, pm);
    k_out<<<dim3(7), 256, 0, stream>>>(pm, out);
}

// Round 2
// 985.042 us; speedup vs baseline: 1.1208x; 1.1208x over previous
//
#include <hip/hip_runtime.h>
#include <math.h>

#define Bc  32
#define Cc  512
#define HWc 784
#define Mc  200
#define Kc  5
#define NCc 50

// ---- k_fg tiling ----
#define PT    16          // pixels per block
#define MT    32          // m per block
#define CK    8           // c per chunk
#define SPL   2           // C split factor (blocks)
#define CSPL  256         // Cc / SPL
#define NCH   32          // CSPL / CK
#define NMT   7           // ceil(200/32)
#define NPT   49          // 784/16
#define ROWS  20          // LDS row stride (floats): 16B-aligned, conflict-free with strided tiles
#define PLANE 644         // LDS c-plane stride = 32*20 + 4 (pad to spread planes across banks)

// ---------------- k_bg: background partial dots (c-split x4) ----------------
// bgpart[z][b][k][hw] = sum_{c in z-range} x[b,c,hw] * cl_norm[k,c]
__global__ __launch_bounds__(256) void k_bg(const float* __restrict__ x,
                                            const float* __restrict__ clut,
                                            float* __restrict__ bgpart) {
    __shared__ float cl[Kc * Cc];
    __shared__ float csum[Kc];
    const int t = threadIdx.x;
    for (int i = t; i < Kc * Cc; i += 256) cl[i] = fminf(fmaxf(clut[i], 0.0f), 1.0f);
    __syncthreads();
    if (t < 160) {
        const int k = t >> 5, l = t & 31;
        float s = 0.0f;
        for (int c = l; c < Cc; c += 32) s += cl[k * Cc + c];
#pragma unroll
        for (int off = 16; off > 0; off >>= 1) s += __shfl_down(s, off, 32);
        if (l == 0) csum[k] = fmaxf(s, 1e-12f);
    }
    __syncthreads();

    const int b = blockIdx.x;
    const int z = blockIdx.z;
    const int hw = blockIdx.y * 256 + t;
    if (hw < HWc) {
        float acc[Kc] = {0.f, 0.f, 0.f, 0.f, 0.f};
        const int cbase = z * 128;
        const float* xb = x + ((size_t)b * Cc + cbase) * HWc + hw;
#pragma unroll 4
        for (int c = 0; c < 128; ++c) {
            const float xv = xb[c * HWc];
#pragma unroll
            for (int k = 0; k < Kc; ++k) acc[k] = fmaf(xv, cl[k * Cc + cbase + c], acc[k]);
        }
#pragma unroll
        for (int k = 0; k < Kc; ++k)
            bgpart[(((z * Bc + b) * Kc) + k) * HWc + hw] = acc[k] / csum[k];
    }
}

// ---------------- k_bgsum: sum z-partials + log ----------------
__global__ void k_bgsum(const float* __restrict__ bgpart, float* __restrict__ bgl) {
    const int i = blockIdx.x * 256 + threadIdx.x;   // over 32*5*784
    const int N = Bc * Kc * HWc;
    if (i < N) {
        const float s = bgpart[i] + bgpart[i + N] + bgpart[i + 2 * N] + bgpart[i + 3 * N];
        bgl[i] = logf(0.3f * s + 1e-10f);
    }
}

// ---------------- k_fg: partial dots + mm sums (the big one) ----------------
// dotp[s][m][b][hw] = sum_{c in s-range} x[b,c,hw]*clamp(mm[m,c,hw])
// Sp[s][m][hw]      = sum_{c in s-range} clamp(mm[m,c,hw])
// Block: 32m x 16pix x all 32b over 256 c.  Thread: strided 8b x 8m x 1pix.
__global__ __launch_bounds__(256, 3) void k_fg(const float* __restrict__ x,
                                               const float* __restrict__ mm,
                                               float* __restrict__ dotp,
                                               float* __restrict__ Sp) {
    __shared__ float ldsX[CK * PLANE];   // [c][row=b][pix], row stride 20, plane stride 644
    __shared__ float ldsM[CK * PLANE];   // [c][row=mrel][pix]

    const int t    = threadIdx.x;
    const int pixl = t & 3;
    const int mg   = (t >> 2) & 3;
    const int bgp  = (t >> 4) & 3;
    const int pixh = t >> 6;
    const int pix  = pixl + 4 * pixh;            // 0..15

    const int mtile = blockIdx.x % NMT;
    const int ptile = (blockIdx.x / NMT) % NPT;
    const int split = blockIdx.x / (NMT * NPT);
    const int pix0  = ptile * PT;
    const int m0    = mtile * MT;
    const int c0    = split * CSPL;

    // staging decode: j = t + 256r -> q=j&3, cx=(j>>2)&7, row=(j>>5) = row0+8r
    const int q    = t & 3;
    const int cx   = (t >> 2) & 7;
    const int row0 = t >> 5;                      // 0..7
    int xo[4], mo[4];
#pragma unroll
    for (int r = 0; r < 4; ++r) {
        const int row = row0 + 8 * r;
        xo[r] = (row * Cc + c0 + cx) * HWc + pix0 + 4 * q;
        const int m = m0 + row;
        mo[r] = ((m < Mc ? m : 0) * Cc + c0 + cx) * HWc + pix0 + 4 * q;
    }
    const int ldsw = cx * PLANE + row0 * ROWS + 4 * q;   // +160 per r
    const int xoff = bgp * ROWS + pix;                   // b = bgp + 4i -> +80 per i
    const int moff = mg * ROWS + pix;                    // m = mg  + 4j -> +80 per j

    float acc[8][8];
#pragma unroll
    for (int i = 0; i < 8; ++i)
#pragma unroll
        for (int j = 0; j < 8; ++j) acc[i][j] = 0.0f;
    float sacc[8] = {0.f, 0.f, 0.f, 0.f, 0.f, 0.f, 0.f, 0.f};

    // prefetch chunk 0
    float4 px[4], pmv[4];
#pragma unroll
    for (int r = 0; r < 4; ++r) {
        px[r]  = *(const float4*)(x + xo[r]);
        pmv[r] = *(const float4*)(mm + mo[r]);
    }

    for (int ch = 0; ch < NCH; ++ch) {
        if (ch) __syncthreads();                 // previous chunk's readers done
#pragma unroll
        for (int r = 0; r < 4; ++r) {
            *(float4*)&ldsX[ldsw + 160 * r] = px[r];
            float4 w = pmv[r];
            w.x = fminf(fmaxf(w.x, 0.0f), 1.0f);
            w.y = fminf(fmaxf(w.y, 0.0f), 1.0f);
            w.z = fminf(fmaxf(w.z, 0.0f), 1.0f);
            w.w = fminf(fmaxf(w.w, 0.0f), 1.0f);
            *(float4*)&ldsM[ldsw + 160 * r] = w;
        }
        __syncthreads();                         // LDS ready
        if (ch + 1 < NCH) {                      // issue next chunk's loads (hidden by compute)
#pragma unroll
            for (int r = 0; r < 4; ++r) {
                xo[r] += CK * HWc;
                mo[r] += CK * HWc;
                px[r]  = *(const float4*)(x + xo[r]);
                pmv[r] = *(const float4*)(mm + mo[r]);
            }
        }
#pragma unroll
        for (int c = 0; c < CK; ++c) {
            float xv[8], mv[8];
#pragma unroll
            for (int i = 0; i < 8; ++i) xv[i] = ldsX[c * PLANE + 80 * i + xoff];
#pragma unroll
            for (int j = 0; j < 8; ++j) mv[j] = ldsM[c * PLANE + 80 * j + moff];
#pragma unroll
            for (int j = 0; j < 8; ++j) sacc[j] += mv[j];
#pragma unroll
            for (int i = 0; i < 8; ++i)
#pragma unroll
                for (int j = 0; j < 8; ++j)
                    acc[i][j] = fmaf(xv[i], mv[j], acc[i][j]);
        }
    }

    // epilogue: store partials (no log yet — k_red finishes)
    const int hw = pix0 + pix;
#pragma unroll
    for (int j = 0; j < 8; ++j) {
        const int m = m0 + mg + 4 * j;
        if (m < Mc) {
            if (bgp == 0) Sp[(split * Mc + m) * HWc + hw] = sacc[j];
#pragma unroll
            for (int i = 0; i < 8; ++i) {
                const int b = bgp + 4 * i;
                dotp[((split * Mc + m) * Bc + b) * HWc + hw] = acc[i][j];
            }
        }
    }
}

// ---------------- k_red: combine splits, log, max(fg,bg), sum pixels, max k ----------------
__global__ __launch_bounds__(256) void k_red(const float* __restrict__ dotp,
                                             const float* __restrict__ Sp,
                                             const float* __restrict__ bgl,
                                             float* __restrict__ pm) {
    const int bm = blockIdx.x;                   // b*200 + m
    const int b = bm / Mc;
    const int m = bm % Mc;
    const int t = threadIdx.x;
    const float* d0 = dotp + ((size_t)m * Bc + b) * HWc;
    const float* d1 = dotp + ((size_t)(Mc + m) * Bc + b) * HWc;
    const float* s0 = Sp + (size_t)m * HWc;
    const float* s1 = Sp + (size_t)(Mc + m) * HWc;
    const float* bgb = bgl + (size_t)b * Kc * HWc;

    float s[Kc] = {0.f, 0.f, 0.f, 0.f, 0.f};
    for (int hw = t; hw < HWc; hw += 256) {
        const float dot = d0[hw] + d1[hw];
        const float S   = s0[hw] + s1[hw];
        const float fgv = logf(0.7f * dot / fmaxf(S, 1e-12f) + 1e-10f);
#pragma unroll
        for (int k = 0; k < Kc; ++k) s[k] += fmaxf(fgv, bgb[k * HWc + hw]);
    }
#pragma unroll
    for (int off = 32; off > 0; off >>= 1) {
#pragma unroll
        for (int k = 0; k < Kc; ++k) s[k] += __shfl_down(s[k], off, 64);
    }
    __shared__ float red[4][Kc];
    const int wv = t >> 6, ln = t & 63;
    if (ln == 0) {
#pragma unroll
        for (int k = 0; k < Kc; ++k) red[wv][k] = s[k];
    }
    __syncthreads();
    if (t == 0) {
        float best = -INFINITY;
#pragma unroll
        for (int k = 0; k < Kc; ++k)
            best = fmaxf(best, red[0][k] + red[1][k] + red[2][k] + red[3][k]);
        pm[bm] = best;
    }
}

// ---------------- k_out: max over NM mixtures ----------------
__global__ void k_out(const float* __restrict__ pm, float* __restrict__ out) {
    const int i = blockIdx.x * 256 + threadIdx.x;   // b*50 + nc
    if (i < Bc * NCc) {
        const int b = i / NCc, nc = i % NCc;
        const float* p = pm + (size_t)b * Mc + nc * 4;
        out[i] = fmaxf(fmaxf(p[0], p[1]), fmaxf(p[2], p[3]));
    }
}

extern "C" void kernel_launch(void* const* d_in, const int* in_sizes, int n_in,
                              void* d_out, int out_size, void* d_ws, size_t ws_size,
                              hipStream_t stream) {
    const float* x    = (const float*)d_in[0];
    const float* mixm = (const float*)d_in[1];
    const float* clut = (const float*)d_in[2];
    float* out = (float*)d_out;

    float* dotp   = (float*)d_ws;                       // 2*200*32*784 = 10,035,200 f
    float* Sp     = dotp + (size_t)SPL * Mc * Bc * HWc; // 2*200*784    =    313,600 f
    float* bgpart = Sp + (size_t)SPL * Mc * HWc;        // 4*32*5*784   =    501,760 f
    float* bgl    = bgpart + (size_t)4 * Bc * Kc * HWc; // 32*5*784     =    125,440 f
    float* pm     = bgl + (size_t)Bc * Kc * HWc;        // 6,400 f      (total ~44 MB)

    k_bg   <<<dim3(Bc, 4, 4), 256, 0, stream>>>(x, clut, bgpart);
    k_bgsum<<<dim3((Bc * Kc * HWc + 255) / 256), 256, 0, stream>>>(bgpart, bgl);
    k_fg   <<<dim3(NMT * NPT * SPL), 256, 0, stream>>>(x, mixm, dotp, Sp);
    k_red  <<<dim3(Bc * Mc), 256, 0, stream>>>(dotp, Sp, bgl, pm);
    k_out  <<<dim3(7), 256, 0, stream>>>(pm, out);
}

// Round 3
// 606.356 us; speedup vs baseline: 1.8207x; 1.6245x over previous
//
#include <hip/hip_runtime.h>
#include <math.h>

#define Bc  32
#define Cc  512
#define HWc 784
#define Mc  200
#define Kc  5
#define NCc 50

// ---- k_fg tiling ----
#define PT    16          // pixels per block
#define MT    32          // m per block
#define CK    8           // c per chunk
#define SPL   2           // C split factor
#define CSPL  256         // Cc / SPL
#define NCH   32          // CSPL / CK
#define NMT   7           // ceil(200/32)
#define NPT   49          // 784/16
#define CHF   4096        // floats per chunk buffer = CK*MT*PT

// async global->LDS, 16B per lane. LDS dest must be lane-contiguous.
__device__ __forceinline__ void gl2lds16(const float* g, float* l) {
    __builtin_amdgcn_global_load_lds(
        (const __attribute__((address_space(1))) void*)g,
        (__attribute__((address_space(3))) void*)l, 16, 0, 0);
}

// ---------------- k_bg: background partial dots (c-split x4) ----------------
__global__ __launch_bounds__(256) void k_bg(const float* __restrict__ x,
                                            const float* __restrict__ clut,
                                            float* __restrict__ bgpart) {
    __shared__ float cl[Kc * Cc];
    __shared__ float csum[Kc];
    const int t = threadIdx.x;
    for (int i = t; i < Kc * Cc; i += 256) cl[i] = clut[i];   // uniform[0,1): clamp is identity
    __syncthreads();
    if (t < 160) {
        const int k = t >> 5, l = t & 31;
        float s = 0.0f;
        for (int c = l; c < Cc; c += 32) s += cl[k * Cc + c];
#pragma unroll
        for (int off = 16; off > 0; off >>= 1) s += __shfl_down(s, off, 32);
        if (l == 0) csum[k] = fmaxf(s, 1e-12f);
    }
    __syncthreads();

    const int b = blockIdx.x;
    const int z = blockIdx.z;
    const int hw = blockIdx.y * 256 + t;
    if (hw < HWc) {
        float acc[Kc] = {0.f, 0.f, 0.f, 0.f, 0.f};
        const int cbase = z * 128;
        const float* xb = x + ((size_t)b * Cc + cbase) * HWc + hw;
#pragma unroll 4
        for (int c = 0; c < 128; ++c) {
            const float xv = xb[c * HWc];
#pragma unroll
            for (int k = 0; k < Kc; ++k) acc[k] = fmaf(xv, cl[k * Cc + cbase + c], acc[k]);
        }
#pragma unroll
        for (int k = 0; k < Kc; ++k)
            bgpart[(((z * Bc + b) * Kc) + k) * HWc + hw] = acc[k] / csum[k];
    }
}

// ---------------- k_bgsum: sum z-partials + log ----------------
__global__ void k_bgsum(const float* __restrict__ bgpart, float* __restrict__ bgl) {
    const int i = blockIdx.x * 256 + threadIdx.x;
    const int N = Bc * Kc * HWc;
    if (i < N) {
        const float s = bgpart[i] + bgpart[i + N] + bgpart[i + 2 * N] + bgpart[i + 3 * N];
        bgl[i] = logf(0.3f * s + 1e-10f);
    }
}

// ---------------- k_fg: partial dots + mm sums ----------------
// dotp[s][m][b][hw] = sum_{c in s-range} x[b,c,hw]*mm[m,c,hw]   (clamp = identity)
// Sp[s][m][hw]      = sum_{c in s-range} mm[m,c,hw]
// Chunk LDS layout [cx][row][pix16], addr = cx*512 + row*16 + pix = 4*j (lane-contiguous for DMA).
// Inner reads: xv[i]=lds[c*512+(bgp+4i)*16+pix] -> 2-way bank alias = free.
__global__ __launch_bounds__(256) __attribute__((amdgpu_waves_per_eu(2, 2)))
void k_fg(const float* __restrict__ x, const float* __restrict__ mm,
          float* __restrict__ dotp, float* __restrict__ Sp) {
    __shared__ float ldsX[2][CHF];
    __shared__ float ldsM[2][CHF];

    const int t    = threadIdx.x;
    const int pixl = t & 3;
    const int mgr  = (t >> 2) & 3;
    const int bgp  = (t >> 4) & 3;
    const int pixh = t >> 6;
    const int pix  = pixl + 4 * pixh;            // 0..15

    const int mtile = blockIdx.x % NMT;
    const int ptile = (blockIdx.x / NMT) % NPT;
    const int split = blockIdx.x / (NMT * NPT);
    const int pix0  = ptile * PT;
    const int m0    = mtile * MT;
    const int c0    = split * CSPL;

    // staging decode: j = t + 256r; q=j&3, row=(j>>2)&31, cx=(t>>7)+2r; LDS float off = 4j
    const int q4   = (t & 3) * 4;
    const int srow = (t >> 2) & 31;
    const int cx0  = t >> 7;
    const int mrow = (m0 + srow < Mc) ? (m0 + srow) : 0;
    const int ldst = 4 * t;                       // + 1024 per r

    int xg = (srow * Cc + c0 + cx0) * HWc + pix0 + q4;
    int mg = (mrow * Cc + c0 + cx0) * HWc + pix0 + q4;

    const int xoff = bgp * PT + pix;              // + 64*i
    const int moff = mgr * PT + pix;              // + 64*j

    float acc[8][8];
#pragma unroll
    for (int i = 0; i < 8; ++i)
#pragma unroll
        for (int j = 0; j < 8; ++j) acc[i][j] = 0.0f;
    float sacc[8] = {0.f, 0.f, 0.f, 0.f, 0.f, 0.f, 0.f, 0.f};

    // prologue: async-load chunk 0 into buffer 0
#pragma unroll
    for (int r = 0; r < 4; ++r) {
        gl2lds16(x + xg + 2 * r * HWc, &ldsX[0][ldst + 1024 * r]);
        gl2lds16(mm + mg + 2 * r * HWc, &ldsM[0][ldst + 1024 * r]);
    }
    xg += CK * HWc;
    mg += CK * HWc;

#pragma unroll 2
    for (int ch = 0; ch < NCH; ++ch) {
        __syncthreads();                          // drains vmcnt: chunk ch resident; prev readers done
        if (ch + 1 < NCH) {                       // prefetch chunk ch+1 into other buffer (async)
            float* bx = &ldsX[(ch + 1) & 1][0];
            float* bm = &ldsM[(ch + 1) & 1][0];
#pragma unroll
            for (int r = 0; r < 4; ++r) {
                gl2lds16(x + xg + 2 * r * HWc, bx + ldst + 1024 * r);
                gl2lds16(mm + mg + 2 * r * HWc, bm + ldst + 1024 * r);
            }
            xg += CK * HWc;
            mg += CK * HWc;
        }
        const float* cbx = &ldsX[ch & 1][0];
        const float* cbm = &ldsM[ch & 1][0];
#pragma unroll
        for (int c = 0; c < CK; ++c) {
            float xv[8], mv[8];
#pragma unroll
            for (int i = 0; i < 8; ++i) xv[i] = cbx[c * 512 + 64 * i + xoff];
#pragma unroll
            for (int j = 0; j < 8; ++j) mv[j] = cbm[c * 512 + 64 * j + moff];
#pragma unroll
            for (int j = 0; j < 8; ++j) sacc[j] += mv[j];
#pragma unroll
            for (int i = 0; i < 8; ++i)
#pragma unroll
                for (int j = 0; j < 8; ++j)
                    acc[i][j] = fmaf(xv[i], mv[j], acc[i][j]);
        }
    }

    // epilogue: store partials
    const int hw = pix0 + pix;
#pragma unroll
    for (int j = 0; j < 8; ++j) {
        const int m = m0 + mgr + 4 * j;
        if (m < Mc) {
            if (bgp == 0) Sp[(split * Mc + m) * HWc + hw] = sacc[j];
#pragma unroll
            for (int i = 0; i < 8; ++i) {
                const int b = bgp + 4 * i;
                dotp[((split * Mc + m) * Bc + b) * HWc + hw] = acc[i][j];
            }
        }
    }
}

// ---------------- k_red: combine splits, log, max(fg,bg), sum pixels, max k ----------------
__global__ __launch_bounds__(256) void k_red(const float* __restrict__ dotp,
                                             const float* __restrict__ Sp,
                                             const float* __restrict__ bgl,
                                             float* __restrict__ pm) {
    const int bm = blockIdx.x;                   // b*200 + m
    const int b = bm / Mc;
    const int m = bm % Mc;
    const int t = threadIdx.x;
    const float* d0 = dotp + ((size_t)m * Bc + b) * HWc;
    const float* d1 = dotp + ((size_t)(Mc + m) * Bc + b) * HWc;
    const float* s0 = Sp + (size_t)m * HWc;
    const float* s1 = Sp + (size_t)(Mc + m) * HWc;
    const float* bgb = bgl + (size_t)b * Kc * HWc;

    float s[Kc] = {0.f, 0.f, 0.f, 0.f, 0.f};
    for (int hw = t; hw < HWc; hw += 256) {
        const float dot = d0[hw] + d1[hw];
        const float S   = s0[hw] + s1[hw];
        const float fgv = logf(0.7f * dot / fmaxf(S, 1e-12f) + 1e-10f);
#pragma unroll
        for (int k = 0; k < Kc; ++k) s[k] += fmaxf(fgv, bgb[k * HWc + hw]);
    }
#pragma unroll
    for (int off = 32; off > 0; off >>= 1) {
#pragma unroll
        for (int k = 0; k < Kc; ++k) s[k] += __shfl_down(s[k], off, 64);
    }
    __shared__ float red[4][Kc];
    const int wv = t >> 6, ln = t & 63;
    if (ln == 0) {
#pragma unroll
        for (int k = 0; k < Kc; ++k) red[wv][k] = s[k];
    }
    __syncthreads();
    if (t == 0) {
        float best = -INFINITY;
#pragma unroll
        for (int k = 0; k < Kc; ++k)
            best = fmaxf(best, red[0][k] + red[1][k] + red[2][k] + red[3][k]);
        pm[bm] = best;
    }
}

// ---------------- k_out: max over NM mixtures ----------------
__global__ void k_out(const float* __restrict__ pm, float* __restrict__ out) {
    const int i = blockIdx.x * 256 + threadIdx.x;   // b*50 + nc
    if (i < Bc * NCc) {
        const int b = i / NCc, nc = i % NCc;
        const float* p = pm + (size_t)b * Mc + nc * 4;
        out[i] = fmaxf(fmaxf(p[0], p[1]), fmaxf(p[2], p[3]));
    }
}

extern "C" void kernel_launch(void* const* d_in, const int* in_sizes, int n_in,
                              void* d_out, int out_size, void* d_ws, size_t ws_size,
                              hipStream_t stream) {
    const float* x    = (const float*)d_in[0];
    const float* mixm = (const float*)d_in[1];
    const float* clut = (const float*)d_in[2];
    float* out = (float*)d_out;

    float* dotp   = (float*)d_ws;                       // 2*200*32*784
    float* Sp     = dotp + (size_t)SPL * Mc * Bc * HWc; // 2*200*784
    float* bgpart = Sp + (size_t)SPL * Mc * HWc;        // 4*32*5*784
    float* bgl    = bgpart + (size_t)4 * Bc * Kc * HWc; // 32*5*784
    float* pm     = bgl + (size_t)Bc * Kc * HWc;        // 6400

    k_bg   <<<dim3(Bc, 4, 4), 256, 0, stream>>>(x, clut, bgpart);
    k_bgsum<<<dim3((Bc * Kc * HWc + 255) / 256), 256, 0, stream>>>(bgpart, bgl);
    k_fg   <<<dim3(NMT * NPT * SPL), 256, 0, stream>>>(x, mixm, dotp, Sp);
    k_red  <<<dim3(Bc * Mc), 256, 0, stream>>>(dotp, Sp, bgl, pm);
    k_out  <<<dim3(7), 256, 0, stream>>>(pm, out);
}

// Round 4
// 577.164 us; speedup vs baseline: 1.9128x; 1.0506x over previous
//
#include <hip/hip_runtime.h>
#include <math.h>

#define Bc  32
#define Cc  512
#define HWc 784
#define Mc  200
#define Kc  5
#define NCc 50

// ---- k_fg tiling ----
#define PTm   16          // pixels per block (full 64B line)
#define MTm   16          // m per block
#define NMB   13          // ceil(200/16) m-blocks (pad to 208)
#define NPB   49          // 784/16 pixel-blocks
#define CKm   32          // c per chunk = MFMA K
#define NCHm  16          // 512/32 chunks
#define RSTR  18          // LDS row stride in dwords (36 bf16): even (8B align), step-18 mod 32 conflict-free
#define XPL   (32*RSTR)   // x plane per pixel = 576 dw
#define MPL   (16*RSTR)   // mm plane per pixel = 288 dw
#define MMBASE (16*XPL)   // mm region start = 9216 dw
#define LDSDW (16*XPL + 16*MPL)   // 13824 dw = 55.3 KB

typedef short s8v __attribute__((ext_vector_type(8)));
typedef float f4v __attribute__((ext_vector_type(4)));

union F8 { uint2 u2[2]; s8v h; };

__device__ __forceinline__ unsigned f2b(float f) {   // fp32 -> bf16 (RNE)
    union { float f; unsigned u; } v; v.f = f;
    return (v.u + 0x7FFFu + ((v.u >> 16) & 1u)) >> 16;
}
__device__ __forceinline__ unsigned pk(float lo, float hi) {
    return f2b(lo) | (f2b(hi) << 16);
}

// ---------------- k_bg: background partial dots (c-split x4) ----------------
__global__ __launch_bounds__(256) void k_bg(const float* __restrict__ x,
                                            const float* __restrict__ clut,
                                            float* __restrict__ bgpart) {
    __shared__ float cl[Kc * Cc];
    __shared__ float csum[Kc];
    const int t = threadIdx.x;
    for (int i = t; i < Kc * Cc; i += 256) cl[i] = clut[i];   // uniform[0,1): clamp = identity
    __syncthreads();
    if (t < 160) {
        const int k = t >> 5, l = t & 31;
        float s = 0.0f;
        for (int c = l; c < Cc; c += 32) s += cl[k * Cc + c];
#pragma unroll
        for (int off = 16; off > 0; off >>= 1) s += __shfl_down(s, off, 32);
        if (l == 0) csum[k] = fmaxf(s, 1e-12f);
    }
    __syncthreads();

    const int b = blockIdx.x;
    const int z = blockIdx.z;
    const int hw = blockIdx.y * 256 + t;
    if (hw < HWc) {
        float acc[Kc] = {0.f, 0.f, 0.f, 0.f, 0.f};
        const int cbase = z * 128;
        const float* xb = x + ((size_t)b * Cc + cbase) * HWc + hw;
#pragma unroll 4
        for (int c = 0; c < 128; ++c) {
            const float xv = xb[c * HWc];
#pragma unroll
            for (int k = 0; k < Kc; ++k) acc[k] = fmaf(xv, cl[k * Cc + cbase + c], acc[k]);
        }
#pragma unroll
        for (int k = 0; k < Kc; ++k)
            bgpart[(((z * Bc + b) * Kc) + k) * HWc + hw] = acc[k] / csum[k];
    }
}

// ---------------- k_bgsum ----------------
__global__ void k_bgsum(const float* __restrict__ bgpart, float* __restrict__ bgl) {
    const int i = blockIdx.x * 256 + threadIdx.x;
    const int N = Bc * Kc * HWc;
    if (i < N) {
        const float s = bgpart[i] + bgpart[i + N] + bgpart[i + 2 * N] + bgpart[i + 3 * N];
        bgl[i] = logf(0.3f * s + 1e-10f);
    }
}

// ---------------- k_fg: MFMA batched per-pixel GEMM ----------------
// fg[m][b][hw] = log(0.7 * dot(x[b,:,hw], mm[m,:,hw]) / max(S[m,hw],1e-12) + 1e-10)
// Block: 16 pix x 16 m x 32 b, full K=512. Wave w owns pixels 4w..4w+3.
// mfma_f32_16x16x32_bf16: A/B lane layout m(n)=lane&15, k=(lane>>4)*8+j; D: col=lane&15, row=quad*4+reg.
__global__ __launch_bounds__(256) __attribute__((amdgpu_waves_per_eu(2, 2)))
void k_fg(const float* __restrict__ x, const float* __restrict__ mm,
          float* __restrict__ fg) {
    __shared__ unsigned lds[LDSDW];

    const int t = threadIdx.x;
    const int mblk = blockIdx.x % NMB;
    const int pix0 = (blockIdx.x / NMB) * PTm;

    // ---- staging decode ----
    // x: 1024 groups (4 c-consec float4s): G = t + 256g -> q=G&3, b=(G>>2)&31, cg=G>>7
    int xoff[4], xl[4];
#pragma unroll
    for (int g = 0; g < 4; ++g) {
        const int G = t + 256 * g;
        const int q = G & 3, b = (G >> 2) & 31, cg = G >> 7;
        xoff[g] = (b * Cc + cg * 4) * HWc + pix0 + 4 * q;
        xl[g]   = 4 * q * XPL + b * RSTR + cg * 2;
    }
    // mm: 512 groups: G = t + 256g -> q=G&3, mr=(G>>2)&15, cg=(G>>6)&7
    int moff[2], ml[2];
    float mzero[2];
#pragma unroll
    for (int g = 0; g < 2; ++g) {
        const int G = t + 256 * g;
        const int q = G & 3, mr = (G >> 2) & 15, cg = (G >> 6) & 7;
        const int mrow = mblk * MTm + mr;
        mzero[g] = (mrow < Mc) ? 1.0f : 0.0f;
        const int mc = (mrow < Mc) ? mrow : (Mc - 1);
        moff[g] = (mc * Cc + cg * 4) * HWc + pix0 + 4 * q;
        ml[g]   = MMBASE + 4 * q * MPL + mr * RSTR + cg * 2;
    }

    // ---- fragment decode ----
    const int lane = t & 63;
    const int w    = t >> 6;                       // wave id = pixel group
    const int row18q = (lane & 15) * RSTR + (lane >> 4) * 4;   // dw offset within plane

    f4v accD[4][2], accS[4];
#pragma unroll
    for (int p = 0; p < 4; ++p) {
        accS[p] = (f4v)0.0f;
#pragma unroll
        for (int bt = 0; bt < 2; ++bt) accD[p][bt] = (f4v)0.0f;
    }
    const s8v ones = {0x3F80, 0x3F80, 0x3F80, 0x3F80, 0x3F80, 0x3F80, 0x3F80, 0x3F80};

#pragma unroll 1
    for (int ch = 0; ch < NCHm; ++ch) {
        __syncthreads();                           // previous chunk's readers done
        // ---- load (batched for memory parallelism) ----
        float4 LX[4][4], LM[2][4];
#pragma unroll
        for (int g = 0; g < 4; ++g)
#pragma unroll
            for (int cc = 0; cc < 4; ++cc)
                LX[g][cc] = *(const float4*)(x + xoff[g] + cc * HWc);
#pragma unroll
        for (int g = 0; g < 2; ++g)
#pragma unroll
            for (int cc = 0; cc < 4; ++cc)
                LM[g][cc] = *(const float4*)(mm + moff[g] + cc * HWc);
#pragma unroll
        for (int g = 0; g < 4; ++g) xoff[g] += CKm * HWc;
#pragma unroll
        for (int g = 0; g < 2; ++g) moff[g] += CKm * HWc;

        // ---- cvt + transposed LDS write (b64, conflict-free) ----
#pragma unroll
        for (int g = 0; g < 4; ++g) {
            const float* f0 = (const float*)&LX[g][0];
            const float* f1 = (const float*)&LX[g][1];
            const float* f2 = (const float*)&LX[g][2];
            const float* f3 = (const float*)&LX[g][3];
#pragma unroll
            for (int p = 0; p < 4; ++p)
                *(uint2*)&lds[xl[g] + p * XPL] =
                    make_uint2(pk(f0[p], f1[p]), pk(f2[p], f3[p]));
        }
#pragma unroll
        for (int g = 0; g < 2; ++g) {
            const float z = mzero[g];
            const float* f0 = (const float*)&LM[g][0];
            const float* f1 = (const float*)&LM[g][1];
            const float* f2 = (const float*)&LM[g][2];
            const float* f3 = (const float*)&LM[g][3];
#pragma unroll
            for (int p = 0; p < 4; ++p)
                *(uint2*)&lds[ml[g] + p * MPL] =
                    make_uint2(pk(f0[p] * z, f1[p] * z), pk(f2[p] * z, f3[p] * z));
        }
        __syncthreads();                           // LDS chunk ready

        // ---- MFMA ----
#pragma unroll
        for (int p = 0; p < 4; ++p) {
            const int pixg = w * 4 + p;
            const unsigned* Xp = &lds[pixg * XPL + row18q];
            const unsigned* Mp = &lds[MMBASE + pixg * MPL + row18q];
            F8 a0, a1, bf;
            a0.u2[0] = *(const uint2*)(Xp);
            a0.u2[1] = *(const uint2*)(Xp + 2);
            a1.u2[0] = *(const uint2*)(Xp + 16 * RSTR);
            a1.u2[1] = *(const uint2*)(Xp + 16 * RSTR + 2);
            bf.u2[0] = *(const uint2*)(Mp);
            bf.u2[1] = *(const uint2*)(Mp + 2);
            accD[p][0] = __builtin_amdgcn_mfma_f32_16x16x32_bf16(a0.h, bf.h, accD[p][0], 0, 0, 0);
            accD[p][1] = __builtin_amdgcn_mfma_f32_16x16x32_bf16(a1.h, bf.h, accD[p][1], 0, 0, 0);
            accS[p]    = __builtin_amdgcn_mfma_f32_16x16x32_bf16(ones, bf.h, accS[p],    0, 0, 0);
        }
    }

    // ---- epilogue: normalize + log + store fg[m][b][hw] ----
    const int m = mblk * MTm + (lane & 15);
    if (m < Mc) {
        const int quad = lane >> 4;
#pragma unroll
        for (int p = 0; p < 4; ++p) {
            const int hw = pix0 + w * 4 + p;
            const float scale = 0.7f / fmaxf(accS[p][0], 1e-12f);
#pragma unroll
            for (int bt = 0; bt < 2; ++bt)
#pragma unroll
                for (int r = 0; r < 4; ++r) {
                    const int b = bt * 16 + quad * 4 + r;
                    fg[((size_t)m * Bc + b) * HWc + hw] =
                        logf(accD[p][bt][r] * scale + 1e-10f);
                }
        }
    }
}

// ---------------- k_red: max(fg,bg_k), sum pixels, max k ----------------
__global__ __launch_bounds__(256) void k_red(const float* __restrict__ fg,
                                             const float* __restrict__ bgl,
                                             float* __restrict__ pm) {
    const int bm = blockIdx.x;                   // b*200 + m
    const int b = bm / Mc;
    const int m = bm % Mc;
    const int t = threadIdx.x;
    const float* fgp = fg + ((size_t)m * Bc + b) * HWc;
    const float* bgb = bgl + (size_t)b * Kc * HWc;

    float s[Kc] = {0.f, 0.f, 0.f, 0.f, 0.f};
    for (int hw = t; hw < HWc; hw += 256) {
        const float f = fgp[hw];
#pragma unroll
        for (int k = 0; k < Kc; ++k) s[k] += fmaxf(f, bgb[k * HWc + hw]);
    }
#pragma unroll
    for (int off = 32; off > 0; off >>= 1) {
#pragma unroll
        for (int k = 0; k < Kc; ++k) s[k] += __shfl_down(s[k], off, 64);
    }
    __shared__ float red[4][Kc];
    const int wv = t >> 6, ln = t & 63;
    if (ln == 0) {
#pragma unroll
        for (int k = 0; k < Kc; ++k) red[wv][k] = s[k];
    }
    __syncthreads();
    if (t == 0) {
        float best = -INFINITY;
#pragma unroll
        for (int k = 0; k < Kc; ++k)
            best = fmaxf(best, red[0][k] + red[1][k] + red[2][k] + red[3][k]);
        pm[bm] = best;
    }
}

// ---------------- k_out ----------------
__global__ void k_out(const float* __restrict__ pm, float* __restrict__ out) {
    const int i = blockIdx.x * 256 + threadIdx.x;   // b*50 + nc
    if (i < Bc * NCc) {
        const int b = i / NCc, nc = i % NCc;
        const float* p = pm + (size_t)b * Mc + nc * 4;
        out[i] = fmaxf(fmaxf(p[0], p[1]), fmaxf(p[2], p[3]));
    }
}

extern "C" void kernel_launch(void* const* d_in, const int* in_sizes, int n_in,
                              void* d_out, int out_size, void* d_ws, size_t ws_size,
                              hipStream_t stream) {
    const float* x    = (const float*)d_in[0];
    const float* mixm = (const float*)d_in[1];
    const float* clut = (const float*)d_in[2];
    float* out = (float*)d_out;

    float* fg     = (float*)d_ws;                        // 200*32*784 = 5,017,600 f
    float* bgpart = fg + (size_t)Mc * Bc * HWc;          // 4*32*5*784 =   501,760 f
    float* bgl    = bgpart + (size_t)4 * Bc * Kc * HWc;  // 32*5*784   =   125,440 f
    float* pm     = bgl + (size_t)Bc * Kc * HWc;         // 6,400 f    (~22.6 MB total)

    k_bg   <<<dim3(Bc, 4, 4), 256, 0, stream>>>(x, clut, bgpart);
    k_bgsum<<<dim3((Bc * Kc * HWc + 255) / 256), 256, 0, stream>>>(bgpart, bgl);
    k_fg   <<<dim3(NMB * NPB), 256, 0, stream>>>(x, mixm, fg);
    k_red  <<<dim3(Bc * Mc), 256, 0, stream>>>(fg, bgl, pm);
    k_out  <<<dim3(7), 256, 0, stream>>>(pm, out);
}